// Round 12
// baseline (378.060 us; speedup 1.0000x reference)
//
#include <hip/hip_runtime.h>

typedef float f4 __attribute__((ext_vector_type(4)));
typedef float f2 __attribute__((ext_vector_type(2)));
typedef float f32x4 __attribute__((ext_vector_type(4)));
typedef short bf16x8 __attribute__((ext_vector_type(8)));
typedef short sh4 __attribute__((ext_vector_type(4)));
typedef unsigned short us4 __attribute__((ext_vector_type(4)));

#define G_TAB 8192
#define SWZ(row, b) ((b) ^ (((row) & 7) << 4))
#define VP 132   // vlin LDS row pitch in shorts (264B: 8B-aligned, bank-skewed)

__device__ __forceinline__ float lrelu(float x) { return x > 0.f ? x : 0.015f * x; }

// Hand-rolled RNE bf16 round (3 VALU ops) — hip_bf16.h's __float2bfloat16 has
// NaN/Inf branches and is ~2-3x more expensive (R10 regression, reverted R11).
__device__ __forceinline__ short f2bf(float x) {
  union { float f; unsigned u; } v; v.f = x;
  unsigned r = v.u + 0x7fff + ((v.u >> 16) & 1);
  return (short)(r >> 16);
}
__device__ __forceinline__ float bf2f(short h) {
  union { float f; unsigned u; } v; v.u = ((unsigned)(unsigned short)h) << 16;
  return v.f;
}
__device__ __forceinline__ float bf2fu(unsigned short h) {
  union { float f; unsigned u; } v; v.u = ((unsigned)h) << 16;
  return v.f;
}

// store f4 as bf16 hi/lo pair into swizzled LDS tile (row pitch 256B)
__device__ __forceinline__ void st_pair(short* Hi, short* Lo, int row, int k, f4 x) {
  sh4 hi, lo;
  #pragma unroll
  for (int c = 0; c < 4; c++) { hi[c] = f2bf(x[c]); lo[c] = f2bf(x[c] - bf2f(hi[c])); }
  int b = row * 256 + SWZ(row, (k >> 3) * 16) + (k & 7) * 2;
  *(sh4*)((char*)Hi + b) = hi;
  *(sh4*)((char*)Lo + b) = lo;
}
__device__ __forceinline__ void st_pair1(short* Hi, short* Lo, int row, int k, float x) {
  short hi = f2bf(x), lo = f2bf(x - bf2f(hi));
  int b = row * 256 + SWZ(row, (k >> 3) * 16) + (k & 7) * 2;
  *(short*)((char*)Hi + b) = hi;
  *(short*)((char*)Lo + b) = lo;
}

// 16-row GEMM core: A from swizzled LDS (hi/lo), B^T hi/lo via SWZ byte
// addressing (pre-swizzled GLOBAL or staged LDS). 3-term split-bf16.
// D-layout (proven): col=fc*16+(l&15), row=w*16+(l>>4)*4+r.
template<int NFC, int CH>
__device__ __forceinline__ void mm16(const short* Ahi, const short* Alo,
    const short* __restrict__ BhT, const short* __restrict__ BlT,
    int w, int l, f32x4* acc) {
  int lr = l & 15, lk = l >> 4;
  #pragma unroll
  for (int fc = 0; fc < NFC; fc++) acc[fc] = (f32x4)0.f;
  #pragma unroll
  for (int ch = 0; ch < CH; ch++) {
    int arow = w * 16 + lr;
    int ab = arow * 256 + SWZ(arow, ch * 64 + lk * 16);
    bf16x8 ah = *(const bf16x8*)((const char*)Ahi + ab);
    bf16x8 al = *(const bf16x8*)((const char*)Alo + ab);
    #pragma unroll
    for (int fc = 0; fc < NFC; fc++) {
      int bcol = fc * 16 + lr;
      int bb = bcol * 256 + SWZ(bcol, ch * 64 + lk * 16);
      bf16x8 bh = *(const bf16x8*)((const char*)BhT + bb);
      bf16x8 bl = *(const bf16x8*)((const char*)BlT + bb);
      acc[fc] = __builtin_amdgcn_mfma_f32_16x16x32_bf16(ah, bh, acc[fc], 0, 0, 0);
      acc[fc] = __builtin_amdgcn_mfma_f32_16x16x32_bf16(al, bh, acc[fc], 0, 0, 0);
      acc[fc] = __builtin_amdgcn_mfma_f32_16x16x32_bf16(ah, bl, acc[fc], 0, 0, 0);
    }
  }
}

// ---------------- prep kernels ----------------

__global__ __launch_bounds__(256) void gather_emb(const int* __restrict__ z,
    const float* __restrict__ emb, float* __restrict__ v, int nf4) {
  int i = blockIdx.x * 256 + threadIdx.x;
  if (i >= nf4) return;
  int a = i >> 5, s = i & 31;
  ((f4*)v)[i] = ((const f4*)emb)[z[a] * 32 + s];
}

__global__ __launch_bounds__(256) void edge_geom(const int* __restrict__ ei,
    const float* __restrict__ pos, float* __restrict__ edc, int E) {
  int e = blockIdx.x * 256 + threadIdx.x;
  if (e >= E) return;
  int r = ei[e], c = ei[E + e];
  float dx = pos[3*r] - pos[3*c];
  float dy = pos[3*r+1] - pos[3*c+1];
  float dz = pos[3*r+2] - pos[3*c+2];
  float d = sqrtf(dx*dx + dy*dy + dz*dz);
  edc[2*e] = d;
  edc[2*e+1] = 0.5f * (cosf(d * 0.6283185307179586f) + 1.0f);
}

__global__ __launch_bounds__(256) void make_starts(const int* __restrict__ row,
    int* __restrict__ starts, int E, int N) {
  int i = blockIdx.x * 256 + threadIdx.x;
  if (i > N) return;
  int lo = 0, hi = E;
  while (lo < hi) { int mid = (lo + hi) >> 1; if (row[mid] < i) lo = mid + 1; else hi = mid; }
  starts[i] = lo;
}

// Pre-swizzled transposed bf16 hi/lo weights, 16384-short (32KB) slots.
// element (col j, K k) -> byte j*256 + ((k>>3)*16 ^ ((j&7)<<4)) + (k&7)*2
// slots: 0-2 w_lin | 3-5 M (prep_M) | 6-8 v_w2 | 9 u_w1 | 10-12 mlp_w2
//        13-15 mlp_w3 | 16-18 mlp_w1 (K pad 64) | 19-21 v_w1
__global__ __launch_bounds__(256) void convert_wt(const float* __restrict__ w_lin,
    const float* __restrict__ vw2, const float* __restrict__ uw1,
    const float* __restrict__ mw1, const float* __restrict__ mw2,
    const float* __restrict__ mw3, const float* __restrict__ vw1,
    short* __restrict__ dhi, short* __restrict__ dlo) {
  int y = blockIdx.y;
  int i = blockIdx.x * 256 + threadIdx.x;   // 0..16383
  int k = i >> 7, j = i & 127;              // j fast: coalesced source reads
  int slot; float x;
  if (y < 3)       { slot = y;     x = w_lin[(size_t)y*16384 + k*128 + j]; }
  else if (y < 6)  { slot = 3 + y; x = vw2[(size_t)(y-3)*16384 + k*128 + j]; }
  else if (y == 6) { slot = 9;     x = (j < 64) ? uw1[k*64 + j] : 0.f; }
  else if (y < 10) { slot = 3 + y; x = mw2[(size_t)(y-7)*16384 + k*128 + j]; }
  else if (y < 13) { slot = 3 + y; x = mw3[(size_t)(y-10)*16384 + k*128 + j]; }
  else if (y < 16) { slot = 3 + y; x = (k < 50) ? mw1[(size_t)(y-13)*6400 + k*128 + j] : 0.f; }
  else             { slot = 3 + y; x = vw1[(size_t)(y-16)*16384 + k*128 + j]; }
  short hi = f2bf(x);
  int ob = j * 256 + (((k >> 3) * 16) ^ ((j & 7) << 4)) + (k & 7) * 2;
  char* bh = (char*)dhi + (size_t)slot * 32768;
  char* bl = (char*)dlo + (size_t)slot * 32768;
  *(short*)(bh + ob) = hi;
  *(short*)(bl + ob) = f2bf(x - bf2f(hi));
}

__global__ __launch_bounds__(128) void make_c1(const float* __restrict__ lball,
    const float* __restrict__ w1all, float* __restrict__ c1all) {
  int l = blockIdx.y;
  const float* lb = lball + (size_t)l * 128;
  const float* w1 = w1all + (size_t)l * 16384;
  int j = threadIdx.x;
  float s = 0.f;
  for (int k = 0; k < 128; k++) s += lb[k] * w1[k * 128 + j];
  c1all[l * 128 + j] = s;
}

// M_l = (lout_w_l + I) @ v_w1_l  -> pre-swizzled transposed hi/lo, slots 3..5
__global__ __launch_bounds__(512) void prep_M(const float* __restrict__ loutw,
    short* __restrict__ whiT, short* __restrict__ wloT) {
  __shared__ __align__(16) short Ahi[16384];
  __shared__ __align__(16) short Alo[16384];
  int tid = threadIdx.x;
  int lay = blockIdx.x;
  int w = tid >> 6, l = tid & 63;
  int lr = l & 15, lk = l >> 4;
  int arow = w * 16 + (l >> 2), sub = l & 3;
  const f4* src = (const f4*)(loutw + (size_t)lay*16384 + (size_t)arow*128 + sub*32);
  #pragma unroll
  for (int q = 0; q < 8; q++) {
    f4 x = src[q];
    int kb = sub * 32 + q * 4;
    #pragma unroll
    for (int cc = 0; cc < 4; cc++) if (arow == kb + cc) x[cc] += 1.0f;  // +I
    st_pair(Ahi, Alo, arow, kb, x);
  }
  __syncthreads();
  f32x4 acc[8];
  mm16<8,4>(Ahi, Alo, whiT + (size_t)(19+lay)*16384, wloT + (size_t)(19+lay)*16384, w, l, acc);
  char* bh = (char*)whiT + (size_t)(3+lay) * 32768;
  char* bl = (char*)wloT + (size_t)(3+lay) * 32768;
  #pragma unroll
  for (int r = 0; r < 4; r++)
    #pragma unroll
    for (int fc = 0; fc < 8; fc++) {
      int row = w*16 + lk*4 + r, col = fc*16 + lr;   // row = K index of M
      float val = acc[fc][r];
      short hi = f2bf(val);
      int ob = col * 256 + (((row >> 3) * 16) ^ ((col & 7) << 4)) + (row & 7) * 2;
      *(short*)(bh + ob) = hi;
      *(short*)(bl + ob) = f2bf(val - bf2f(hi));
    }
}

// Table build: fused 3-stage MLP via MFMA -> bf16 table. 128 pts/block.
__global__ __launch_bounds__(512) void table_mfma(
    const short* __restrict__ whiT, const short* __restrict__ wloT,
    const float* __restrict__ mb1, const float* __restrict__ mb2,
    const float* __restrict__ mb3, unsigned short* __restrict__ tables) {
  __shared__ __align__(16) short Ahi[16384];
  __shared__ __align__(16) short Alo[16384];
  __shared__ __align__(16) short Bhi[16384];
  __shared__ __align__(16) short Blo[16384];
  int tid = threadIdx.x;
  int lay = blockIdx.y;
  int p0 = blockIdx.x * 128;
  int w = tid >> 6, l = tid & 63;
  int lr = l & 15, lk = l >> 4;
  int prow = w * 16 + (l >> 2), sub = l & 3;
  const float delta = 5.0f / (G_TAB - 1);
  {
    float d = (p0 + prow) * delta;
    #pragma unroll
    for (int q = 0; q < 4; q++) {
      f4 x;
      #pragma unroll
      for (int cc = 0; cc < 4; cc++) {
        int k = sub * 16 + q * 4 + cc;
        float t = d - k * (5.0f / 49.0f);
        x[cc] = (k < 50) ? expf(-48.02f * t * t) : 0.f;
      }
      st_pair(Ahi, Alo, prow, sub * 16 + q * 4, x);
    }
  }
  __syncthreads();
  f32x4 acc[8];
  mm16<8,2>(Ahi, Alo, whiT + (size_t)(16+lay)*16384, wloT + (size_t)(16+lay)*16384, w, l, acc);
  #pragma unroll
  for (int r = 0; r < 4; r++)
    #pragma unroll
    for (int fc = 0; fc < 8; fc++)
      st_pair1(Bhi, Blo, w*16 + lk*4 + r, fc*16 + lr,
               lrelu(acc[fc][r] + mb1[lay*128 + fc*16 + lr]));
  __syncthreads();
  mm16<8,4>(Bhi, Blo, whiT + (size_t)(10+lay)*16384, wloT + (size_t)(10+lay)*16384, w, l, acc);
  #pragma unroll
  for (int r = 0; r < 4; r++)
    #pragma unroll
    for (int fc = 0; fc < 8; fc++)
      st_pair1(Ahi, Alo, w*16 + lk*4 + r, fc*16 + lr,
               lrelu(acc[fc][r] + mb2[lay*128 + fc*16 + lr]));
  __syncthreads();
  mm16<8,4>(Ahi, Alo, whiT + (size_t)(13+lay)*16384, wloT + (size_t)(13+lay)*16384, w, l, acc);
  unsigned short* tb = tables + (size_t)lay * G_TAB * 128;
  #pragma unroll
  for (int r = 0; r < 4; r++)
    #pragma unroll
    for (int fc = 0; fc < 8; fc++)
      tb[(size_t)(p0 + w*16 + lk*4 + r) * 128 + fc*16 + lr] =
          (unsigned short)f2bf(acc[fc][r] + mb3[lay*128 + fc*16 + lr]);
}

// ---------------- main-loop kernels ----------------

// FUSED per-graph: vlin = v @ w_lin (gemm, R9-proven core) -> bf16-hi in LDS;
// barrier; gather S[a] = sum_nbr vlin[c]*Tnn(d)*C with vlin from LDS.
// One block per graph (gemm tile == graph; edges never leave the graph).
// Phase 2: wave w handles atoms w*32..w*32+31; R9 gather inner structure
// (64 lanes/atom, 2-way edge split, 4-edge pipeline, NN bf16 table from L2).
// XCD affinity: block p -> graph (p%8)*32 + p/8.
__global__ __launch_bounds__(256) void vlin_gather(
    const float* __restrict__ v, const short* __restrict__ BhS,
    const short* __restrict__ BlS, const int* __restrict__ ei,
    const int* __restrict__ starts, const float* __restrict__ edc,
    const unsigned short* __restrict__ tb, float* __restrict__ S,
    float* __restrict__ deg, int E) {
  __shared__ __align__(16) short Bhi[16384];
  __shared__ __align__(16) unsigned short vlds[128 * VP];
  int tid = threadIdx.x;
  int p = blockIdx.x;
  int g = ((p & 7) << 5) + (p >> 3);
  size_t row0 = (size_t)g * 128;
  #pragma unroll
  for (int s = 0; s < 8; s++)
    ((bf16x8*)Bhi)[tid + 256*s] = ((const bf16x8*)BhS)[tid + 256*s];
  __syncthreads();
  int w = tid >> 6, l = tid & 63, lr = l & 15, lk = l >> 4;
  const char* BlB = (const char*)BlS;
  // ---- phase 1: vlin gemm (R9 gemm128b core), out -> LDS bf16-hi ----
  #pragma unroll
  for (int half = 0; half < 2; half++) {
    int rbase = half * 64 + w * 16;
    const float* ap0 = v + (row0 + rbase + lr) * 128;
    bf16x8 ah[4], al[4];
    #pragma unroll
    for (int ch = 0; ch < 4; ch++) {
      const f4* ap = (const f4*)(ap0 + ch*32 + lk*8);
      f4 x0 = ap[0], x1 = ap[1];
      #pragma unroll
      for (int c = 0; c < 4; c++) {
        short h0 = f2bf(x0[c]);
        ah[ch][c] = h0; al[ch][c] = f2bf(x0[c] - bf2f(h0));
        short h1 = f2bf(x1[c]);
        ah[ch][c+4] = h1; al[ch][c+4] = f2bf(x1[c] - bf2f(h1));
      }
    }
    f32x4 acc[8];
    #pragma unroll
    for (int fc = 0; fc < 8; fc++) acc[fc] = (f32x4)0.f;
    #pragma unroll
    for (int ch = 0; ch < 4; ch++)
      #pragma unroll
      for (int fc = 0; fc < 8; fc++) {
        int bcol = fc*16 + lr;
        int bb = bcol*256 + SWZ(bcol, ch*64 + lk*16);
        bf16x8 bh = *(const bf16x8*)((const char*)Bhi + bb);
        bf16x8 bl = *(const bf16x8*)(BlB + bb);
        acc[fc] = __builtin_amdgcn_mfma_f32_16x16x32_bf16(ah[ch], bh, acc[fc], 0, 0, 0);
        acc[fc] = __builtin_amdgcn_mfma_f32_16x16x32_bf16(al[ch], bh, acc[fc], 0, 0, 0);
        acc[fc] = __builtin_amdgcn_mfma_f32_16x16x32_bf16(ah[ch], bl, acc[fc], 0, 0, 0);
      }
    #pragma unroll
    for (int r = 0; r < 4; r++) {
      int row = rbase + lk*4 + r;
      #pragma unroll
      for (int fc = 0; fc < 8; fc++)
        vlds[row * VP + fc*16 + lr] = (unsigned short)f2bf(acc[fc][r]);
    }
  }
  __syncthreads();
  // ---- phase 2: gather from LDS vlin ----
  int half2 = l >> 5, fl = l & 31;
  int j0 = fl * 4;
  const float sc = (float)(G_TAB - 1) / 5.0f;
  for (int ai = 0; ai < 32; ai++) {
    int arow = w * 32 + ai;
    int a = (int)row0 + arow;
    int s0 = starts[a], ee = starts[a + 1];
    int mid = s0 + ((ee - s0 + 1) >> 1);
    int e0 = half2 ? mid : s0;
    int e1 = half2 ? ee : mid;
    f4 acc = (f4)0.f;
    int e = e0;
    for (; e + 3 < e1; e += 4) {
      int cc[4]; f2 dd[4];
      #pragma unroll
      for (int q = 0; q < 4; q++) {
        cc[q] = ei[E + e + q] - (int)row0;
        dd[q] = *(const f2*)&edc[2*(e+q)];
      }
      us4 vl[4], t[4];
      #pragma unroll
      for (int q = 0; q < 4; q++) {
        int i0 = (int)(dd[q][0] * sc + 0.5f);
        if (i0 > G_TAB - 1) i0 = G_TAB - 1;
        t[q] = *(const us4*)&tb[(size_t)i0 * 128 + j0];
        vl[q] = *(const us4*)&vlds[cc[q] * VP + j0];
      }
      #pragma unroll
      for (int q = 0; q < 4; q++) {
        f4 T, V;
        #pragma unroll
        for (int c4 = 0; c4 < 4; c4++) { T[c4] = bf2fu(t[q][c4]); V[c4] = bf2fu(vl[q][c4]); }
        acc += V * (T * dd[q][1]);
      }
    }
    for (; e < e1; e++) {
      int c0 = ei[E + e] - (int)row0;
      f2 dc0 = *(const f2*)&edc[2 * e];
      int i0 = (int)(dc0[0] * sc + 0.5f);
      if (i0 > G_TAB - 1) i0 = G_TAB - 1;
      us4 t = *(const us4*)&tb[(size_t)i0 * 128 + j0];
      us4 vl = *(const us4*)&vlds[c0 * VP + j0];
      f4 T, V;
      #pragma unroll
      for (int c4 = 0; c4 < 4; c4++) { T[c4] = bf2fu(t[c4]); V[c4] = bf2fu(vl[c4]); }
      acc += V * (T * dc0[1]);
    }
    #pragma unroll
    for (int c4 = 0; c4 < 4; c4++) acc[c4] += __shfl_xor(acc[c4], 32);
    if (half2 == 0) *(f4*)&S[(size_t)a * 128 + j0] = acc;
    if (l == 0) deg[a] = (float)(ee - s0);
  }
}

// out = op(A @ W + bias).  (R9-proven; ABF/OBF kept for template compat)
template<int ACT, int ACC, int BIAS, int ABF, int OBF>
__global__ __launch_bounds__(256) void gemm128b(
    const void* __restrict__ Ain, const short* __restrict__ BhS,
    const short* __restrict__ BlS, const float* __restrict__ bias,
    const float* __restrict__ bias2, const float* __restrict__ rs,
    void* __restrict__ outv) {
  __shared__ __align__(16) short Bhi[16384];
  int tid = threadIdx.x;
  int p = blockIdx.x;
  size_t row0 = (size_t)(((p & 7) << 5) + (p >> 3)) * 128;
  #pragma unroll
  for (int s = 0; s < 8; s++)
    ((bf16x8*)Bhi)[tid + 256*s] = ((const bf16x8*)BhS)[tid + 256*s];
  __syncthreads();
  int w = tid >> 6, l = tid & 63, lr = l & 15, lk = l >> 4;
  const char* BlB = (const char*)BlS;
  #pragma unroll
  for (int half = 0; half < 2; half++) {
    int rbase = half * 64 + w * 16;
    bf16x8 ah[4], al[4];
    if (ABF) {
      const short* ap0 = (const short*)Ain + (row0 + rbase + lr) * 128;
      #pragma unroll
      for (int ch = 0; ch < 4; ch++)
        ah[ch] = *(const bf16x8*)(ap0 + ch*32 + lk*8);
    } else {
      const float* ap0 = (const float*)Ain + (row0 + rbase + lr) * 128;
      #pragma unroll
      for (int ch = 0; ch < 4; ch++) {
        const f4* ap = (const f4*)(ap0 + ch*32 + lk*8);
        f4 x0 = ap[0], x1 = ap[1];
        #pragma unroll
        for (int c = 0; c < 4; c++) {
          short h0 = f2bf(x0[c]);
          ah[ch][c] = h0; al[ch][c] = f2bf(x0[c] - bf2f(h0));
          short h1 = f2bf(x1[c]);
          ah[ch][c+4] = h1; al[ch][c+4] = f2bf(x1[c] - bf2f(h1));
        }
      }
    }
    f32x4 acc[8];
    #pragma unroll
    for (int fc = 0; fc < 8; fc++) acc[fc] = (f32x4)0.f;
    #pragma unroll
    for (int ch = 0; ch < 4; ch++)
      #pragma unroll
      for (int fc = 0; fc < 8; fc++) {
        int bcol = fc*16 + lr;
        int bb = bcol*256 + SWZ(bcol, ch*64 + lk*16);
        bf16x8 bh = *(const bf16x8*)((const char*)Bhi + bb);
        bf16x8 bl = *(const bf16x8*)(BlB + bb);
        acc[fc] = __builtin_amdgcn_mfma_f32_16x16x32_bf16(ah[ch], bh, acc[fc], 0, 0, 0);
        if (!ABF)
          acc[fc] = __builtin_amdgcn_mfma_f32_16x16x32_bf16(al[ch], bh, acc[fc], 0, 0, 0);
        acc[fc] = __builtin_amdgcn_mfma_f32_16x16x32_bf16(ah[ch], bl, acc[fc], 0, 0, 0);
      }
    #pragma unroll
    for (int r = 0; r < 4; r++) {
      size_t grow = row0 + rbase + lk*4 + r;
      float rsv = (BIAS == 3) ? rs[grow] : 0.f;
      #pragma unroll
      for (int fc = 0; fc < 8; fc++) {
        int col = fc*16 + lr;
        float val = acc[fc][r];
        if (BIAS == 1) val += bias[col];
        if (BIAS == 3) val += rsv * bias[col] + bias2[col];
        if (ACT) val = lrelu(val);
        if (OBF) {
          ((short*)outv)[grow * 128 + col] = f2bf(val);
        } else {
          float* op = (float*)outv + grow * 128 + col;
          if (ACC) val += *op;
          *op = val;
        }
      }
    }
  }
}

// y[a] = sum_m lrelu((v@u_w1)[a][m]+ub1[m])*uw2[m]; B-hi LDS 16KB, B-lo global.
__global__ __launch_bounds__(256) void readout_b(const float* __restrict__ v,
    const short* __restrict__ Bh9, const short* __restrict__ Bl9,
    const float* __restrict__ ub1, const float* __restrict__ uw2,
    float* __restrict__ y) {
  __shared__ __align__(16) short Bh[8192];
  int tid = threadIdx.x;
  int p = blockIdx.x;
  size_t row0 = (size_t)(((p & 7) << 5) + (p >> 3)) * 128;
  #pragma unroll
  for (int s = 0; s < 4; s++)
    ((bf16x8*)Bh)[tid + 256*s] = ((const bf16x8*)Bh9)[tid + 256*s];
  __syncthreads();
  int w = tid >> 6, l = tid & 63, lr = l & 15, lk = l >> 4;
  const char* BlB = (const char*)Bl9;
  #pragma unroll
  for (int half = 0; half < 2; half++) {
    int rbase = half * 64 + w * 16;
    const float* ap0 = v + (row0 + rbase + lr) * 128;
    bf16x8 ah[4], al[4];
    #pragma unroll
    for (int ch = 0; ch < 4; ch++) {
      const f4* ap = (const f4*)(ap0 + ch*32 + lk*8);
      f4 x0 = ap[0], x1 = ap[1];
      #pragma unroll
      for (int c = 0; c < 4; c++) {
        short h0 = f2bf(x0[c]);
        ah[ch][c] = h0; al[ch][c] = f2bf(x0[c] - bf2f(h0));
        short h1 = f2bf(x1[c]);
        ah[ch][c+4] = h1; al[ch][c+4] = f2bf(x1[c] - bf2f(h1));
      }
    }
    f32x4 acc[4];
    #pragma unroll
    for (int fc = 0; fc < 4; fc++) acc[fc] = (f32x4)0.f;
    #pragma unroll
    for (int ch = 0; ch < 4; ch++)
      #pragma unroll
      for (int fc = 0; fc < 4; fc++) {
        int bcol = fc*16 + lr;
        int bb = bcol*256 + SWZ(bcol, ch*64 + lk*16);
        bf16x8 bh = *(const bf16x8*)((const char*)Bh + bb);
        bf16x8 bl = *(const bf16x8*)(BlB + bb);
        acc[fc] = __builtin_amdgcn_mfma_f32_16x16x32_bf16(ah[ch], bh, acc[fc], 0, 0, 0);
        acc[fc] = __builtin_amdgcn_mfma_f32_16x16x32_bf16(al[ch], bh, acc[fc], 0, 0, 0);
        acc[fc] = __builtin_amdgcn_mfma_f32_16x16x32_bf16(ah[ch], bl, acc[fc], 0, 0, 0);
      }
    #pragma unroll
    for (int r = 0; r < 4; r++) {
      float sv = 0.f;
      #pragma unroll
      for (int fc = 0; fc < 4; fc++) {
        int col = fc*16 + lr;
        sv += lrelu(acc[fc][r] + ub1[col]) * uw2[col];
      }
      sv += __shfl_xor(sv, 1); sv += __shfl_xor(sv, 2);
      sv += __shfl_xor(sv, 4); sv += __shfl_xor(sv, 8);
      if (lr == 0) y[row0 + rbase + lk*4 + r] = sv;
    }
  }
}

__global__ __launch_bounds__(256) void graph_mean(const float* __restrict__ y,
    const float* __restrict__ ub2, float* __restrict__ out) {
  __shared__ float red[256];
  int tid = threadIdx.x;
  red[tid] = y[blockIdx.x * 256 + tid];
  __syncthreads();
  for (int s = 64; s > 0; s >>= 1) {
    if ((tid & 127) < s) red[tid] += red[tid + s];
    __syncthreads();
  }
  if ((tid & 127) == 0)
    out[blockIdx.x * 2 + (tid >> 7)] = red[tid] * (1.0f / 128.0f) + ub2[0];
}

extern "C" void kernel_launch(void* const* d_in, const int* in_sizes, int n_in,
                              void* d_out, int out_size, void* d_ws, size_t ws_size,
                              hipStream_t stream) {
  const int*   z     = (const int*)d_in[0];
  const float* pos   = (const float*)d_in[1];
  const int*   ei    = (const int*)d_in[3];
  const float* emb   = (const float*)d_in[4];
  const float* w_lin = (const float*)d_in[5];
  const float* mw1   = (const float*)d_in[6];
  const float* mb1   = (const float*)d_in[7];
  const float* mw2   = (const float*)d_in[8];
  const float* mb2   = (const float*)d_in[9];
  const float* mw3   = (const float*)d_in[10];
  const float* mb3   = (const float*)d_in[11];
  const float* loutw = (const float*)d_in[12];
  const float* loutb = (const float*)d_in[13];
  const float* vw1   = (const float*)d_in[14];
  const float* vb1   = (const float*)d_in[15];
  const float* vw2   = (const float*)d_in[16];
  const float* vb2   = (const float*)d_in[17];
  const float* uw1   = (const float*)d_in[18];
  const float* ub1   = (const float*)d_in[19];
  const float* uw2   = (const float*)d_in[20];
  const float* ub2   = (const float*)d_in[21];
  int N = in_sizes[0];
  int E = in_sizes[3] / 2;
  float* out = (float*)d_out;

  size_t off = 0;
  auto alloc = [&](size_t bytes) -> void* {
    void* p = (char*)d_ws + off;
    off += (bytes + 255) & ~(size_t)255;
    return p;
  };
  float* v      = (float*)alloc((size_t)N * 128 * 4);
  float* Sbuf   = (float*)alloc((size_t)N * 128 * 4);
  float* bufC   = (float*)alloc((size_t)N * 128 * 4);
  unsigned short* tables = (unsigned short*)alloc((size_t)3 * G_TAB * 128 * 2);
  short* whiT   = (short*)alloc((size_t)22 * 16384 * 2);
  short* wloT   = (short*)alloc((size_t)22 * 16384 * 2);
  float* c1s    = (float*)alloc(3 * 128 * 4);
  float* deg    = (float*)alloc((size_t)N * 4);
  float* edc    = (float*)alloc((size_t)E * 8);
  int*   starts = (int*)alloc((size_t)(N + 1) * 4);
  float* y      = (float*)alloc((size_t)N * 4);

  gather_emb<<<(N * 32 + 255) / 256, 256, 0, stream>>>(z, emb, v, N * 32);
  edge_geom<<<(E + 255) / 256, 256, 0, stream>>>(ei, pos, edc, E);
  make_starts<<<(N + 256) / 256, 256, 0, stream>>>(ei, starts, E, N);
  convert_wt<<<dim3(64, 19), 256, 0, stream>>>(w_lin, vw2, uw1, mw1, mw2, mw3, vw1,
                                               whiT, wloT);
  prep_M<<<3, 512, 0, stream>>>(loutw, whiT, wloT);
  make_c1<<<dim3(1, 3), 128, 0, stream>>>(loutb, vw1, c1s);
  table_mfma<<<dim3(G_TAB / 128, 3), 512, 0, stream>>>(whiT, wloT, mb1, mb2, mb3, tables);

  for (int l = 0; l < 3; l++) {
    // fused: vlin = v @ w_lin_l (LDS) ; S = gather(vlin)
    vlin_gather<<<N / 128, 256, 0, stream>>>(
        v, whiT + (size_t)l * 16384, wloT + (size_t)l * 16384,
        ei, starts, edc, tables + (size_t)l * G_TAB * 128, Sbuf, deg, E);
    // t = lrelu(S @ M_l + deg*c1_l + vb1_l)
    gemm128b<1, 0, 3, 0, 0><<<N / 128, 256, 0, stream>>>(
        Sbuf, whiT + (size_t)(3 + l) * 16384, wloT + (size_t)(3 + l) * 16384,
        c1s + (size_t)l * 128, vb1 + (size_t)l * 128, deg, bufC);
    // v += t @ v_w2_l + vb2_l
    gemm128b<0, 1, 1, 0, 0><<<N / 128, 256, 0, stream>>>(
        bufC, whiT + (size_t)(6 + l) * 16384, wloT + (size_t)(6 + l) * 16384,
        vb2 + (size_t)l * 128, nullptr, nullptr, v);
  }
  readout_b<<<N / 128, 256, 0, stream>>>(v, whiT + (size_t)9 * 16384,
                                         wloT + (size_t)9 * 16384, ub1, uw2, y);
  graph_mean<<<N / 256, 256, 0, stream>>>(y, ub2, out);
}

// Round 13
// 268.213 us; speedup vs baseline: 1.4096x; 1.4096x over previous
//
#include <hip/hip_runtime.h>

typedef float f4 __attribute__((ext_vector_type(4)));
typedef float f2 __attribute__((ext_vector_type(2)));
typedef float f32x4 __attribute__((ext_vector_type(4)));
typedef short bf16x8 __attribute__((ext_vector_type(8)));
typedef short sh4 __attribute__((ext_vector_type(4)));
typedef unsigned short us4 __attribute__((ext_vector_type(4)));

#define G_TAB 8192
#define SWZ(row, b) ((b) ^ (((row) & 7) << 4))

__device__ __forceinline__ float lrelu(float x) { return x > 0.f ? x : 0.015f * x; }

// Hand-rolled RNE bf16 round (3 VALU ops) — proven best (R10/R11 A/B).
__device__ __forceinline__ short f2bf(float x) {
  union { float f; unsigned u; } v; v.f = x;
  unsigned r = v.u + 0x7fff + ((v.u >> 16) & 1);
  return (short)(r >> 16);
}
__device__ __forceinline__ float bf2f(short h) {
  union { float f; unsigned u; } v; v.u = ((unsigned)(unsigned short)h) << 16;
  return v.f;
}
__device__ __forceinline__ float bf2fu(unsigned short h) {
  union { float f; unsigned u; } v; v.u = ((unsigned)h) << 16;
  return v.f;
}

// store f4 as bf16 hi/lo pair into swizzled LDS tile (row pitch 256B)
__device__ __forceinline__ void st_pair(short* Hi, short* Lo, int row, int k, f4 x) {
  sh4 hi, lo;
  #pragma unroll
  for (int c = 0; c < 4; c++) { hi[c] = f2bf(x[c]); lo[c] = f2bf(x[c] - bf2f(hi[c])); }
  int b = row * 256 + SWZ(row, (k >> 3) * 16) + (k & 7) * 2;
  *(sh4*)((char*)Hi + b) = hi;
  *(sh4*)((char*)Lo + b) = lo;
}
__device__ __forceinline__ void st_pair1(short* Hi, short* Lo, int row, int k, float x) {
  short hi = f2bf(x), lo = f2bf(x - bf2f(hi));
  int b = row * 256 + SWZ(row, (k >> 3) * 16) + (k & 7) * 2;
  *(short*)((char*)Hi + b) = hi;
  *(short*)((char*)Lo + b) = lo;
}

// 16-row GEMM core: A from swizzled LDS (hi/lo), B^T hi/lo via SWZ byte
// addressing (pre-swizzled GLOBAL or staged LDS). 3-term split-bf16.
// D-layout (proven): col=fc*16+(l&15), row=w*16+(l>>4)*4+r.
template<int NFC, int CH>
__device__ __forceinline__ void mm16(const short* Ahi, const short* Alo,
    const short* __restrict__ BhT, const short* __restrict__ BlT,
    int w, int l, f32x4* acc) {
  int lr = l & 15, lk = l >> 4;
  #pragma unroll
  for (int fc = 0; fc < NFC; fc++) acc[fc] = (f32x4)0.f;
  #pragma unroll
  for (int ch = 0; ch < CH; ch++) {
    int arow = w * 16 + lr;
    int ab = arow * 256 + SWZ(arow, ch * 64 + lk * 16);
    bf16x8 ah = *(const bf16x8*)((const char*)Ahi + ab);
    bf16x8 al = *(const bf16x8*)((const char*)Alo + ab);
    #pragma unroll
    for (int fc = 0; fc < NFC; fc++) {
      int bcol = fc * 16 + lr;
      int bb = bcol * 256 + SWZ(bcol, ch * 64 + lk * 16);
      bf16x8 bh = *(const bf16x8*)((const char*)BhT + bb);
      bf16x8 bl = *(const bf16x8*)((const char*)BlT + bb);
      acc[fc] = __builtin_amdgcn_mfma_f32_16x16x32_bf16(ah, bh, acc[fc], 0, 0, 0);
      acc[fc] = __builtin_amdgcn_mfma_f32_16x16x32_bf16(al, bh, acc[fc], 0, 0, 0);
      acc[fc] = __builtin_amdgcn_mfma_f32_16x16x32_bf16(ah, bl, acc[fc], 0, 0, 0);
    }
  }
}

// ---------------- prep kernels ----------------

__global__ __launch_bounds__(256) void gather_emb(const int* __restrict__ z,
    const float* __restrict__ emb, float* __restrict__ v, int nf4) {
  int i = blockIdx.x * 256 + threadIdx.x;
  if (i >= nf4) return;
  int a = i >> 5, s = i & 31;
  ((f4*)v)[i] = ((const f4*)emb)[z[a] * 32 + s];
}

__global__ __launch_bounds__(256) void edge_geom(const int* __restrict__ ei,
    const float* __restrict__ pos, float* __restrict__ edc, int E) {
  int e = blockIdx.x * 256 + threadIdx.x;
  if (e >= E) return;
  int r = ei[e], c = ei[E + e];
  float dx = pos[3*r] - pos[3*c];
  float dy = pos[3*r+1] - pos[3*c+1];
  float dz = pos[3*r+2] - pos[3*c+2];
  float d = sqrtf(dx*dx + dy*dy + dz*dz);
  edc[2*e] = d;
  edc[2*e+1] = 0.5f * (cosf(d * 0.6283185307179586f) + 1.0f);
}

__global__ __launch_bounds__(256) void make_starts(const int* __restrict__ row,
    int* __restrict__ starts, int E, int N) {
  int i = blockIdx.x * 256 + threadIdx.x;
  if (i > N) return;
  int lo = 0, hi = E;
  while (lo < hi) { int mid = (lo + hi) >> 1; if (row[mid] < i) lo = mid + 1; else hi = mid; }
  starts[i] = lo;
}

// Pre-swizzled transposed bf16 hi/lo weights, 16384-short (32KB) slots.
// element (col j, K k) -> byte j*256 + ((k>>3)*16 ^ ((j&7)<<4)) + (k&7)*2
// slots: 0-2 w_lin | 3-5 M (prep_M) | 6-8 v_w2 | 9 u_w1 | 10-12 mlp_w2
//        13-15 mlp_w3 | 16-18 mlp_w1 (K pad 64) | 19-21 v_w1
__global__ __launch_bounds__(256) void convert_wt(const float* __restrict__ w_lin,
    const float* __restrict__ vw2, const float* __restrict__ uw1,
    const float* __restrict__ mw1, const float* __restrict__ mw2,
    const float* __restrict__ mw3, const float* __restrict__ vw1,
    short* __restrict__ dhi, short* __restrict__ dlo) {
  int y = blockIdx.y;
  int i = blockIdx.x * 256 + threadIdx.x;   // 0..16383
  int k = i >> 7, j = i & 127;              // j fast: coalesced source reads
  int slot; float x;
  if (y < 3)       { slot = y;     x = w_lin[(size_t)y*16384 + k*128 + j]; }
  else if (y < 6)  { slot = 3 + y; x = vw2[(size_t)(y-3)*16384 + k*128 + j]; }
  else if (y == 6) { slot = 9;     x = (j < 64) ? uw1[k*64 + j] : 0.f; }
  else if (y < 10) { slot = 3 + y; x = mw2[(size_t)(y-7)*16384 + k*128 + j]; }
  else if (y < 13) { slot = 3 + y; x = mw3[(size_t)(y-10)*16384 + k*128 + j]; }
  else if (y < 16) { slot = 3 + y; x = (k < 50) ? mw1[(size_t)(y-13)*6400 + k*128 + j] : 0.f; }
  else             { slot = 3 + y; x = vw1[(size_t)(y-16)*16384 + k*128 + j]; }
  short hi = f2bf(x);
  int ob = j * 256 + (((k >> 3) * 16) ^ ((j & 7) << 4)) + (k & 7) * 2;
  char* bh = (char*)dhi + (size_t)slot * 32768;
  char* bl = (char*)dlo + (size_t)slot * 32768;
  *(short*)(bh + ob) = hi;
  *(short*)(bl + ob) = f2bf(x - bf2f(hi));
}

__global__ __launch_bounds__(128) void make_c1(const float* __restrict__ lball,
    const float* __restrict__ w1all, float* __restrict__ c1all) {
  int l = blockIdx.y;
  const float* lb = lball + (size_t)l * 128;
  const float* w1 = w1all + (size_t)l * 16384;
  int j = threadIdx.x;
  float s = 0.f;
  for (int k = 0; k < 128; k++) s += lb[k] * w1[k * 128 + j];
  c1all[l * 128 + j] = s;
}

// M_l = (lout_w_l + I) @ v_w1_l  -> pre-swizzled transposed hi/lo, slots 3..5
__global__ __launch_bounds__(512) void prep_M(const float* __restrict__ loutw,
    short* __restrict__ whiT, short* __restrict__ wloT) {
  __shared__ __align__(16) short Ahi[16384];
  __shared__ __align__(16) short Alo[16384];
  int tid = threadIdx.x;
  int lay = blockIdx.x;
  int w = tid >> 6, l = tid & 63;
  int lr = l & 15, lk = l >> 4;
  int arow = w * 16 + (l >> 2), sub = l & 3;
  const f4* src = (const f4*)(loutw + (size_t)lay*16384 + (size_t)arow*128 + sub*32);
  #pragma unroll
  for (int q = 0; q < 8; q++) {
    f4 x = src[q];
    int kb = sub * 32 + q * 4;
    #pragma unroll
    for (int cc = 0; cc < 4; cc++) if (arow == kb + cc) x[cc] += 1.0f;  // +I
    st_pair(Ahi, Alo, arow, kb, x);
  }
  __syncthreads();
  f32x4 acc[8];
  mm16<8,4>(Ahi, Alo, whiT + (size_t)(19+lay)*16384, wloT + (size_t)(19+lay)*16384, w, l, acc);
  char* bh = (char*)whiT + (size_t)(3+lay) * 32768;
  char* bl = (char*)wloT + (size_t)(3+lay) * 32768;
  #pragma unroll
  for (int r = 0; r < 4; r++)
    #pragma unroll
    for (int fc = 0; fc < 8; fc++) {
      int row = w*16 + lk*4 + r, col = fc*16 + lr;   // row = K index of M
      float val = acc[fc][r];
      short hi = f2bf(val);
      int ob = col * 256 + (((row >> 3) * 16) ^ ((col & 7) << 4)) + (row & 7) * 2;
      *(short*)(bh + ob) = hi;
      *(short*)(bl + ob) = f2bf(val - bf2f(hi));
    }
}

// Table build: fused 3-stage MLP via MFMA -> bf16 table. 128 pts/block.
__global__ __launch_bounds__(512) void table_mfma(
    const short* __restrict__ whiT, const short* __restrict__ wloT,
    const float* __restrict__ mb1, const float* __restrict__ mb2,
    const float* __restrict__ mb3, unsigned short* __restrict__ tables) {
  __shared__ __align__(16) short Ahi[16384];
  __shared__ __align__(16) short Alo[16384];
  __shared__ __align__(16) short Bhi[16384];
  __shared__ __align__(16) short Blo[16384];
  int tid = threadIdx.x;
  int lay = blockIdx.y;
  int p0 = blockIdx.x * 128;
  int w = tid >> 6, l = tid & 63;
  int lr = l & 15, lk = l >> 4;
  int prow = w * 16 + (l >> 2), sub = l & 3;
  const float delta = 5.0f / (G_TAB - 1);
  {
    float d = (p0 + prow) * delta;
    #pragma unroll
    for (int q = 0; q < 4; q++) {
      f4 x;
      #pragma unroll
      for (int cc = 0; cc < 4; cc++) {
        int k = sub * 16 + q * 4 + cc;
        float t = d - k * (5.0f / 49.0f);
        x[cc] = (k < 50) ? expf(-48.02f * t * t) : 0.f;
      }
      st_pair(Ahi, Alo, prow, sub * 16 + q * 4, x);
    }
  }
  __syncthreads();
  f32x4 acc[8];
  mm16<8,2>(Ahi, Alo, whiT + (size_t)(16+lay)*16384, wloT + (size_t)(16+lay)*16384, w, l, acc);
  #pragma unroll
  for (int r = 0; r < 4; r++)
    #pragma unroll
    for (int fc = 0; fc < 8; fc++)
      st_pair1(Bhi, Blo, w*16 + lk*4 + r, fc*16 + lr,
               lrelu(acc[fc][r] + mb1[lay*128 + fc*16 + lr]));
  __syncthreads();
  mm16<8,4>(Bhi, Blo, whiT + (size_t)(10+lay)*16384, wloT + (size_t)(10+lay)*16384, w, l, acc);
  #pragma unroll
  for (int r = 0; r < 4; r++)
    #pragma unroll
    for (int fc = 0; fc < 8; fc++)
      st_pair1(Ahi, Alo, w*16 + lk*4 + r, fc*16 + lr,
               lrelu(acc[fc][r] + mb2[lay*128 + fc*16 + lr]));
  __syncthreads();
  mm16<8,4>(Ahi, Alo, whiT + (size_t)(13+lay)*16384, wloT + (size_t)(13+lay)*16384, w, l, acc);
  unsigned short* tb = tables + (size_t)lay * G_TAB * 128;
  #pragma unroll
  for (int r = 0; r < 4; r++)
    #pragma unroll
    for (int fc = 0; fc < 8; fc++)
      tb[(size_t)(p0 + w*16 + lk*4 + r) * 128 + fc*16 + lr] =
          (unsigned short)f2bf(acc[fc][r] + mb3[lay*128 + fc*16 + lr]);
}

// ---------------- main-loop kernels ----------------

// out = op(A @ W + bias); A per-lane from global; B-hi staged LDS (32KB),
// B-lo read from pre-swizzled global (L1-resident 32KB).
// XCD affinity: block p -> graph (p%8)*32 + p/8.
template<int ACT, int ACC, int BIAS>
__global__ __launch_bounds__(256) void gemm128b(
    const float* __restrict__ A, const short* __restrict__ BhS,
    const short* __restrict__ BlS, const float* __restrict__ bias,
    const float* __restrict__ bias2, const float* __restrict__ rs,
    float* __restrict__ out) {
  __shared__ __align__(16) short Bhi[16384];
  int tid = threadIdx.x;
  int p = blockIdx.x;
  size_t row0 = (size_t)(((p & 7) << 5) + (p >> 3)) * 128;
  #pragma unroll
  for (int s = 0; s < 8; s++)
    ((bf16x8*)Bhi)[tid + 256*s] = ((const bf16x8*)BhS)[tid + 256*s];
  __syncthreads();
  int w = tid >> 6, l = tid & 63, lr = l & 15, lk = l >> 4;
  const char* BlB = (const char*)BlS;
  #pragma unroll
  for (int half = 0; half < 2; half++) {
    int rbase = half * 64 + w * 16;
    const float* ap0 = A + (row0 + rbase + lr) * 128;
    bf16x8 ah[4], al[4];
    #pragma unroll
    for (int ch = 0; ch < 4; ch++) {
      const f4* ap = (const f4*)(ap0 + ch*32 + lk*8);
      f4 x0 = ap[0], x1 = ap[1];
      #pragma unroll
      for (int c = 0; c < 4; c++) {
        short h0 = f2bf(x0[c]);
        ah[ch][c] = h0; al[ch][c] = f2bf(x0[c] - bf2f(h0));
        short h1 = f2bf(x1[c]);
        ah[ch][c+4] = h1; al[ch][c+4] = f2bf(x1[c] - bf2f(h1));
      }
    }
    f32x4 acc[8];
    #pragma unroll
    for (int fc = 0; fc < 8; fc++) acc[fc] = (f32x4)0.f;
    #pragma unroll
    for (int ch = 0; ch < 4; ch++)
      #pragma unroll
      for (int fc = 0; fc < 8; fc++) {
        int bcol = fc*16 + lr;
        int bb = bcol*256 + SWZ(bcol, ch*64 + lk*16);
        bf16x8 bh = *(const bf16x8*)((const char*)Bhi + bb);
        bf16x8 bl = *(const bf16x8*)(BlB + bb);
        acc[fc] = __builtin_amdgcn_mfma_f32_16x16x32_bf16(ah[ch], bh, acc[fc], 0, 0, 0);
        acc[fc] = __builtin_amdgcn_mfma_f32_16x16x32_bf16(al[ch], bh, acc[fc], 0, 0, 0);
        acc[fc] = __builtin_amdgcn_mfma_f32_16x16x32_bf16(ah[ch], bl, acc[fc], 0, 0, 0);
      }
    #pragma unroll
    for (int r = 0; r < 4; r++) {
      size_t grow = row0 + rbase + lk*4 + r;
      float rsv = (BIAS == 3) ? rs[grow] : 0.f;
      #pragma unroll
      for (int fc = 0; fc < 8; fc++) {
        int col = fc*16 + lr;
        float val = acc[fc][r];
        if (BIAS == 1) val += bias[col];
        if (BIAS == 3) val += rsv * bias[col] + bias2[col];
        if (ACT) val = lrelu(val);
        float* op = &out[grow * 128 + col];
        if (ACC) val += *op;
        *op = val;
      }
    }
  }
}

// S[a] = sum over edges (a,c) of vlin[c] * Tnn(d) * C.   Nearest-neighbor bf16
// table @ G_TAB=8192. 64 lanes per atom: halves split the edge range, combine
// via shfl_xor(32). 4-edge pipeline inside each half.
__global__ __launch_bounds__(256) void edge_gather(
    const int* __restrict__ ei, const int* __restrict__ starts,
    const float* __restrict__ edc, const float* __restrict__ vlin,
    const unsigned short* __restrict__ tb, float* __restrict__ S,
    float* __restrict__ deg, int E, int N) {
  int tid = threadIdx.x;
  int lane = tid & 63, grp = tid >> 6;       // 4 atoms per 256-thread block
  int half = lane >> 5, fl = lane & 31;
  int p = blockIdx.x;
  int o = ((p & 7) << 10) + (p >> 3);        // XCD affinity (8192 blocks)
  int a = o * 4 + grp;
  if (a >= N) return;
  int s = starts[a], ee = starts[a + 1];
  int mid = s + ((ee - s + 1) >> 1);
  int e0 = half ? mid : s;
  int e1 = half ? ee : mid;
  int j0 = fl * 4;
  const float sc = (float)(G_TAB - 1) / 5.0f;
  f4 acc = (f4)0.f;
  int e = e0;
  for (; e + 3 < e1; e += 4) {
    int cc[4]; f2 dd[4];
    #pragma unroll
    for (int q = 0; q < 4; q++) { cc[q] = ei[E + e + q]; dd[q] = *(const f2*)&edc[2*(e+q)]; }
    f4 vl[4]; us4 t[4];
    #pragma unroll
    for (int q = 0; q < 4; q++) {
      int i0 = (int)(dd[q][0] * sc + 0.5f);
      if (i0 > G_TAB - 1) i0 = G_TAB - 1;
      t[q] = *(const us4*)&tb[(size_t)i0 * 128 + j0];
      vl[q] = *(const f4*)&vlin[(size_t)cc[q] * 128 + j0];
    }
    #pragma unroll
    for (int q = 0; q < 4; q++) {
      f4 T;
      #pragma unroll
      for (int c4 = 0; c4 < 4; c4++) T[c4] = bf2fu(t[q][c4]);
      acc += vl[q] * (T * dd[q][1]);
    }
  }
  for (; e < e1; e++) {
    int c0 = ei[E + e];
    f2 dc0 = *(const f2*)&edc[2 * e];
    int i0 = (int)(dc0[0] * sc + 0.5f);
    if (i0 > G_TAB - 1) i0 = G_TAB - 1;
    us4 t = *(const us4*)&tb[(size_t)i0 * 128 + j0];
    f4 vl = *(const f4*)&vlin[(size_t)c0 * 128 + j0];
    f4 T;
    #pragma unroll
    for (int c4 = 0; c4 < 4; c4++) T[c4] = bf2fu(t[c4]);
    acc += vl * (T * dc0[1]);
  }
  #pragma unroll
  for (int c4 = 0; c4 < 4; c4++) acc[c4] += __shfl_xor(acc[c4], 32);
  if (half == 0) *(f4*)&S[(size_t)a * 128 + j0] = acc;
  if (lane == 0) deg[a] = (float)(ee - s);
}

// y[a] = sum_m lrelu((v@u_w1)[a][m]+ub1[m])*uw2[m]; B-hi LDS 16KB, B-lo global.
__global__ __launch_bounds__(256) void readout_b(const float* __restrict__ v,
    const short* __restrict__ Bh9, const short* __restrict__ Bl9,
    const float* __restrict__ ub1, const float* __restrict__ uw2,
    float* __restrict__ y) {
  __shared__ __align__(16) short Bh[8192];
  int tid = threadIdx.x;
  int p = blockIdx.x;
  size_t row0 = (size_t)(((p & 7) << 5) + (p >> 3)) * 128;
  #pragma unroll
  for (int s = 0; s < 4; s++)
    ((bf16x8*)Bh)[tid + 256*s] = ((const bf16x8*)Bh9)[tid + 256*s];
  __syncthreads();
  int w = tid >> 6, l = tid & 63, lr = l & 15, lk = l >> 4;
  const char* BlB = (const char*)Bl9;
  #pragma unroll
  for (int half = 0; half < 2; half++) {
    int rbase = half * 64 + w * 16;
    const float* ap0 = v + (row0 + rbase + lr) * 128;
    bf16x8 ah[4], al[4];
    #pragma unroll
    for (int ch = 0; ch < 4; ch++) {
      const f4* ap = (const f4*)(ap0 + ch*32 + lk*8);
      f4 x0 = ap[0], x1 = ap[1];
      #pragma unroll
      for (int c = 0; c < 4; c++) {
        short h0 = f2bf(x0[c]);
        ah[ch][c] = h0; al[ch][c] = f2bf(x0[c] - bf2f(h0));
        short h1 = f2bf(x1[c]);
        ah[ch][c+4] = h1; al[ch][c+4] = f2bf(x1[c] - bf2f(h1));
      }
    }
    f32x4 acc[4];
    #pragma unroll
    for (int fc = 0; fc < 4; fc++) acc[fc] = (f32x4)0.f;
    #pragma unroll
    for (int ch = 0; ch < 4; ch++)
      #pragma unroll
      for (int fc = 0; fc < 4; fc++) {
        int bcol = fc*16 + lr;
        int bb = bcol*256 + SWZ(bcol, ch*64 + lk*16);
        bf16x8 bh = *(const bf16x8*)((const char*)Bh + bb);
        bf16x8 bl = *(const bf16x8*)(BlB + bb);
        acc[fc] = __builtin_amdgcn_mfma_f32_16x16x32_bf16(ah[ch], bh, acc[fc], 0, 0, 0);
        acc[fc] = __builtin_amdgcn_mfma_f32_16x16x32_bf16(al[ch], bh, acc[fc], 0, 0, 0);
        acc[fc] = __builtin_amdgcn_mfma_f32_16x16x32_bf16(ah[ch], bl, acc[fc], 0, 0, 0);
      }
    #pragma unroll
    for (int r = 0; r < 4; r++) {
      float sv = 0.f;
      #pragma unroll
      for (int fc = 0; fc < 4; fc++) {
        int col = fc*16 + lr;
        sv += lrelu(acc[fc][r] + ub1[col]) * uw2[col];
      }
      sv += __shfl_xor(sv, 1); sv += __shfl_xor(sv, 2);
      sv += __shfl_xor(sv, 4); sv += __shfl_xor(sv, 8);
      if (lr == 0) y[row0 + rbase + lk*4 + r] = sv;
    }
  }
}

__global__ __launch_bounds__(256) void graph_mean(const float* __restrict__ y,
    const float* __restrict__ ub2, float* __restrict__ out) {
  __shared__ float red[256];
  int tid = threadIdx.x;
  red[tid] = y[blockIdx.x * 256 + tid];
  __syncthreads();
  for (int s = 64; s > 0; s >>= 1) {
    if ((tid & 127) < s) red[tid] += red[tid + s];
    __syncthreads();
  }
  if ((tid & 127) == 0)
    out[blockIdx.x * 2 + (tid >> 7)] = red[tid] * (1.0f / 128.0f) + ub2[0];
}

extern "C" void kernel_launch(void* const* d_in, const int* in_sizes, int n_in,
                              void* d_out, int out_size, void* d_ws, size_t ws_size,
                              hipStream_t stream) {
  const int*   z     = (const int*)d_in[0];
  const float* pos   = (const float*)d_in[1];
  const int*   ei    = (const int*)d_in[3];
  const float* emb   = (const float*)d_in[4];
  const float* w_lin = (const float*)d_in[5];
  const float* mw1   = (const float*)d_in[6];
  const float* mb1   = (const float*)d_in[7];
  const float* mw2   = (const float*)d_in[8];
  const float* mb2   = (const float*)d_in[9];
  const float* mw3   = (const float*)d_in[10];
  const float* mb3   = (const float*)d_in[11];
  const float* loutw = (const float*)d_in[12];
  const float* loutb = (const float*)d_in[13];
  const float* vw1   = (const float*)d_in[14];
  const float* vb1   = (const float*)d_in[15];
  const float* vw2   = (const float*)d_in[16];
  const float* vb2   = (const float*)d_in[17];
  const float* uw1   = (const float*)d_in[18];
  const float* ub1   = (const float*)d_in[19];
  const float* uw2   = (const float*)d_in[20];
  const float* ub2   = (const float*)d_in[21];
  int N = in_sizes[0];
  int E = in_sizes[3] / 2;
  float* out = (float*)d_out;

  size_t off = 0;
  auto alloc = [&](size_t bytes) -> void* {
    void* p = (char*)d_ws + off;
    off += (bytes + 255) & ~(size_t)255;
    return p;
  };
  float* v      = (float*)alloc((size_t)N * 128 * 4);
  float* bufA   = (float*)alloc((size_t)N * 128 * 4);
  float* bufB   = (float*)alloc((size_t)N * 128 * 4);
  float* bufC   = (float*)alloc((size_t)N * 128 * 4);
  unsigned short* tables = (unsigned short*)alloc((size_t)3 * G_TAB * 128 * 2);
  short* whiT   = (short*)alloc((size_t)22 * 16384 * 2);
  short* wloT   = (short*)alloc((size_t)22 * 16384 * 2);
  float* c1s    = (float*)alloc(3 * 128 * 4);
  float* deg    = (float*)alloc((size_t)N * 4);
  float* edc    = (float*)alloc((size_t)E * 8);
  int*   starts = (int*)alloc((size_t)(N + 1) * 4);
  float* y      = (float*)alloc((size_t)N * 4);

  gather_emb<<<(N * 32 + 255) / 256, 256, 0, stream>>>(z, emb, v, N * 32);
  edge_geom<<<(E + 255) / 256, 256, 0, stream>>>(ei, pos, edc, E);
  make_starts<<<(N + 256) / 256, 256, 0, stream>>>(ei, starts, E, N);
  convert_wt<<<dim3(64, 19), 256, 0, stream>>>(w_lin, vw2, uw1, mw1, mw2, mw3, vw1,
                                               whiT, wloT);
  prep_M<<<3, 512, 0, stream>>>(loutw, whiT, wloT);
  make_c1<<<dim3(1, 3), 128, 0, stream>>>(loutb, vw1, c1s);
  table_mfma<<<dim3(G_TAB / 128, 3), 512, 0, stream>>>(whiT, wloT, mb1, mb2, mb3, tables);

  for (int l = 0; l < 3; l++) {
    gemm128b<0, 0, 0><<<N / 128, 256, 0, stream>>>(
        v, whiT + (size_t)l * 16384, wloT + (size_t)l * 16384,
        nullptr, nullptr, nullptr, bufA);
    edge_gather<<<N / 4, 256, 0, stream>>>(ei, starts, edc, bufA,
                                           tables + (size_t)l * G_TAB * 128,
                                           bufB, deg, E, N);
    gemm128b<1, 0, 3><<<N / 128, 256, 0, stream>>>(
        bufB, whiT + (size_t)(3 + l) * 16384, wloT + (size_t)(3 + l) * 16384,
        c1s + (size_t)l * 128, vb1 + (size_t)l * 128, deg, bufC);
    gemm128b<0, 1, 1><<<N / 128, 256, 0, stream>>>(
        bufC, whiT + (size_t)(6 + l) * 16384, wloT + (size_t)(6 + l) * 16384,
        vb2 + (size_t)l * 128, nullptr, nullptr, v);
  }
  readout_b<<<N / 128, 256, 0, stream>>>(v, whiT + (size_t)9 * 16384,
                                         wloT + (size_t)9 * 16384, ub1, uw2, y);
  graph_mean<<<N / 256, 256, 0, stream>>>(y, ub2, out);
}